// Round 8
// baseline (3460.530 us; speedup 1.0000x reference)
//
#include <hip/hip_runtime.h>
#include <cstdint>
#include <cstddef>

// Problem constants
#define N_NEU   4096
#define N_IN    1024
#define B_SZ    8
#define T_STEPS 500
#define NSLICE  16
#define NBLK    (B_SZ * NSLICE)     // 128 blocks, 256 threads, 1 post/thread
#define FF_WORDS (B_SZ * T_STEPS * 16)

// ws layout:
//   [0)      u64 rec[2][8][128]   16 KB  (tagged half-mask records {tag:32,mask:32};
//                                         src = slice*4 + wave, covers posts src*64..+64)
//   [16384)  u64 tmask[64]        512 B  (per-64-group exc-type bit masks)
//   [16896)  u64 ffmask[B*T*16]   512 KB (input-spike bitmasks)
#define WS_REC_OFF   0
#define WS_TM_OFF    16384
#define WS_FFM_OFF   16896

__global__ __launch_bounds__(64) void snn_init(const int* __restrict__ ci,
                                               unsigned long long* __restrict__ rec,
                                               unsigned long long* __restrict__ tmask) {
    const int k = blockIdx.x, l = threadIdx.x;   // 64 blocks x 64 threads
    unsigned long long m = __ballot(ci[(k << 6) + l] == 0);
    if (l == 0) tmask[k] = m;
    const int idx = (k << 6) + l;
    if (idx < 2048) rec[idx] = 0ULL;             // tags = 0
}

// input spikes (B,T,NI) -> bitmask words, 64 elems per word, ascending order
__global__ __launch_bounds__(256) void snn_ffmask(const float* __restrict__ inspk,
                                                  unsigned long long* __restrict__ ffmask) {
    int gid = blockIdx.x * 256 + threadIdx.x;
    int wid = gid >> 6, lane = gid & 63;
    int nw  = (gridDim.x * 256) >> 6;
    for (int w = wid; w < FF_WORDS; w += nw) {
        float v = inspk[(size_t)w * 64 + lane];
        unsigned long long m = __ballot(v > 0.5f);
        if (lane == 0) ffmask[w] = m;
    }
}

// Extract set bits of a distributed mask (lane l holds word l, bit b -> index
// l*64+b) into lds as typed entries (idx<<2)|ty starting at `start`, globally
// ascending. ty: is_ff ? 2 : (tm_exc bit ? 0 : 1). Returns start + count.
__device__ __forceinline__ int extract_typed(unsigned long long m,
                                             unsigned long long tm_exc,
                                             int* lds, int lane, int start, int is_ff) {
    int pc  = __popcll(m);
    int sum = pc;
#pragma unroll
    for (int d = 1; d < 64; d <<= 1) {
        int o = __shfl_up(sum, d, 64);
        if (lane >= d) sum += o;
    }
    int off   = start + sum - pc;   // exclusive prefix + base
    int total = __shfl(sum, 63, 64);
    int base  = lane << 6;
    while (m) {
        int bit = __builtin_ctzll(m);
        int ty  = is_ff ? 2 : (((tm_exc >> bit) & 1ULL) ? 0 : 1);
        lds[off++] = ((base + bit) << 2) | ty;
        m &= m - 1ULL;
    }
    return start + total;
}

// Combined typed gather over one padded list; exc/inh/ff accumulate into
// SEPARATE accumulators (each internally ascending -> bit-exact vs the
// reference's separate matmuls/einsum). ty3 sentinels contribute nowhere.
__device__ __forceinline__ void gather3(const int* __restrict__ lst, int npad,
                                        const float* __restrict__ bw,   // W + i
                                        const float* __restrict__ bf,   // Wff + i
                                        float se, float si, float sff,
                                        float* oe, float* oi, float* of_) {
#pragma clang fp contract(off)
    float ae = 0.0f, ai = 0.0f, af = 0.0f;
    for (int k = 0; k < npad; k += 64) {
        int   e[64];
        float w[64];
#pragma unroll
        for (int u = 0; u < 64; ++u) e[u] = lst[k + u];
#pragma unroll
        for (int u = 0; u < 64; ++u) {
            const int ty = e[u] & 3;
            const float* bp = (ty == 2) ? bf : bw;
            w[u] = bp[(size_t)(e[u] >> 2) << 12];
        }
#pragma unroll
        for (int u = 0; u < 64; ++u) {
            const int ty = e[u] & 3;
            const float sc = (ty == 0) ? se : ((ty == 1) ? si : ((ty == 2) ? sff : 0.0f));
            const float p  = w[u] * sc;      // per-element product rounding = W_eff
            ae = (ty == 0) ? ae + p : ae;
            ai = (ty == 1) ? ai + p : ai;
            af = (ty == 2) ? af + p : af;
        }
    }
    *oe = ae; *oi = ai; *of_ = af;
}

__global__ __launch_bounds__(256, 1) void snn_run(
    const float* __restrict__ W,       // (N,N) row j = presyn
    const float* __restrict__ Wff,     // (NI,N)
    const float* __restrict__ sf,      // (2,2)
    const float* __restrict__ sfff,    // (1,2)
    const int*   __restrict__ ci,      // (N)
    float*       __restrict__ out,     // (B,T,N)
    const unsigned long long* __restrict__ ffmask,
    const unsigned long long* __restrict__ tmask_g,
    unsigned long long* __restrict__ rec)
{
#pragma clang fp contract(off)
    const int tid   = threadIdx.x;
    const int lane  = tid & 63;
    const int wv    = tid >> 6;
    const int bid   = blockIdx.x;
    // slice from bits {0,1,2,6} (slice%8 pins W col-slice groups per XCD),
    // batch from bits {3,4,5}
    const int slice = (((bid >> 6) & 1) << 3) | (bid & 7);
    const int b     = (bid >> 3) & 7;
    const int i     = (slice << 8) + (wv << 6) + lane;    // my post neuron
    const int c     = ci[i];

    const float s_exc = sf[c];
    const float s_inh = sf[2 + c];
    const float s_ff  = sfff[c];

    const unsigned long long my_tm = tmask_g[lane];   // wave0's extract role

    __shared__ int lds_c[N_NEU + N_IN + 64];
    __shared__ int s_n;

    // state lives in registers for all 500 steps (1 post/thread)
    float v = -70.0f, rf = 0.0f;
    float h0 = 0.0f, h1 = 0.0f, h2 = 0.0f, h3 = 0.0f;
    float g0 = 0.0f, g1 = 0.0f, g2 = 0.0f, g3 = 0.0f;

    const float aR0 = expf(-0.1f / 0.5f);
    const float aR1 = expf(-0.1f / 2.0f);
    const float aD0 = expf(-0.1f / 2.0f);
    const float aD1 = expf(-0.1f / 100.0f);
    const float aD2 = expf(-0.1f / 5.0f);
    const float kmem   = c ? (0.1f / 10.0f) : (0.1f / 20.0f);
    const float rsteps = c ? 10.0f : 20.0f;

    for (int t = 0; t < T_STEPS; ++t) {
        if (wv == 0) {
            // static ff-mask load issued BEFORE the poll (hides under it)
            const unsigned long long mf =
                (lane < 16) ? ffmask[((size_t)b * T_STEPS + t) * 16 + lane] : 0ULL;

            // ---- one-hop sync: poll tagged records; payload arrives with the
            // tag (u64 atomicity -> no tearing). No producer drain, no seq.
            unsigned long long mask = 0ULL;
            if (t > 0) {
                const unsigned long long* rp = rec + ((size_t)(t & 1) * 8 + b) * 128;
                unsigned long long r0, r1;
                for (;;) {
                    r0 = __hip_atomic_load(rp + 2 * lane,     __ATOMIC_RELAXED,
                                           __HIP_MEMORY_SCOPE_AGENT);
                    r1 = __hip_atomic_load(rp + 2 * lane + 1, __ATOMIC_RELAXED,
                                           __HIP_MEMORY_SCOPE_AGENT);
                    bool ok = ((int)(r0 >> 32) >= t) && ((int)(r1 >> 32) >= t);
                    if (__ballot(ok) == ~0ULL) break;
                    __builtin_amdgcn_s_sleep(1);
                }
                // src l covers posts l*64.. -> lane l's word is exactly word l
                mask = (r0 & 0xffffffffULL) | ((r1 & 0xffffffffULL) << 32);
            }

            // combined list: rec entries (ty0/1) then ff entries (ty2), padded
            const int n1 = extract_typed(mask, my_tm, lds_c, lane, 0, 0);
            const int n2 = extract_typed(mf, 0ULL, lds_c, lane, n1, 1);
            const int padcnt = (-n2) & 63;
            if (lane < padcnt) lds_c[n2 + lane] = 3;   // sentinel: idx 0, ty 3
            if (lane == 0) s_n = n2;
        }
        __syncthreads();   // A: list + count visible; also isolates lds_c reuse

        float exc, inh, ffd;
        gather3(lds_c, (s_n + 63) & ~63, W + i, Wff + i,
                s_exc, s_inh, s_ff, &exc, &inh, &ffd);

        // ---- neuron update (identical fp op sequence to R1–R7: bit-exact) ----
        const float d0 = exc;
        const float d1 = 0.5f * exc;
        const float d2 = inh;
        const float d3 = ffd;

        h0 = fmaf(h0, aR0, d0);
        h1 = fmaf(h1, aR1, d1);
        h2 = fmaf(h2, aR0, d2);
        h3 = fmaf(h3, aR0, d3);
        g0 = fmaf(g0, aD0, (1.0f - aD0) * h0);
        g1 = fmaf(g1, aD1, (1.0f - aD1) * h1);
        g2 = fmaf(g2, aD2, (1.0f - aD2) * h2);
        g3 = fmaf(g3, aD0, (1.0f - aD0) * h3);

        const float p0 = g0 * (0.0f - v);
        const float p1 = g1 * (0.0f - v);
        const float p2 = g2 * (-80.0f - v);
        const float p3 = g3 * (0.0f - v);
        const float Isyn = ((p0 + p1) + p2) + p3;

        float vn = fmaf(kmem, (-70.0f - v) + Isyn / 10.0f, v);
        const bool refr = rf > 0.0f;
        if (refr) vn = -65.0f;
        const float sn = (!refr && (vn > -50.0f)) ? 1.0f : 0.0f;
        const bool spk = sn > 0.5f;
        v  = spk ? -65.0f : vn;
        rf = spk ? rsteps : fmaxf(rf - 1.0f, 0.0f);

        // publish FIRST (visibility-critical), out store after (fire-and-forget)
        const unsigned long long sm = __ballot(spk);
        if (lane == 0) {
            unsigned long long* rp = rec + ((size_t)((t + 1) & 1) * 8 + b) * 128
                                   + 2 * ((slice << 2) | wv);
            const unsigned long long tag = ((unsigned long long)(t + 1)) << 32;
            __hip_atomic_store(rp,     tag | (sm & 0xffffffffULL),
                               __ATOMIC_RELAXED, __HIP_MEMORY_SCOPE_AGENT);
            __hip_atomic_store(rp + 1, tag | (sm >> 32),
                               __ATOMIC_RELAXED, __HIP_MEMORY_SCOPE_AGENT);
        }
        out[((size_t)b * T_STEPS + t) * N_NEU + i] = sn;
        // No barrier B needed: wave0's next poll can't pass until this block's
        // waves publish t+1 (they are among the 64 sources), and they publish
        // only after their last lds_c read — so wave0's rewrite is safe.
    }
}

extern "C" void kernel_launch(void* const* d_in, const int* in_sizes, int n_in,
                              void* d_out, int out_size, void* d_ws, size_t ws_size,
                              hipStream_t stream) {
    const float* inspk = (const float*)d_in[0];
    const float* W     = (const float*)d_in[1];
    const float* Wff   = (const float*)d_in[2];
    const float* sf    = (const float*)d_in[3];
    const float* sfff  = (const float*)d_in[4];
    const int*   ci    = (const int*)d_in[5];

    float* out = (float*)d_out;
    unsigned long long* rec    = (unsigned long long*)((char*)d_ws + WS_REC_OFF);
    unsigned long long* tmask  = (unsigned long long*)((char*)d_ws + WS_TM_OFF);
    unsigned long long* ffmask = (unsigned long long*)((char*)d_ws + WS_FFM_OFF);

    snn_init<<<64, 64, 0, stream>>>(ci, rec, tmask);
    snn_ffmask<<<1000, 256, 0, stream>>>(inspk, ffmask);
    snn_run<<<NBLK, 256, 0, stream>>>(W, Wff, sf, sfff, ci, out,
                                      ffmask, tmask, rec);
}

// Round 9
// 2322.187 us; speedup vs baseline: 1.4902x; 1.4902x over previous
//
#include <hip/hip_runtime.h>
#include <cstdint>
#include <cstddef>

// Problem constants
#define N_NEU   4096
#define N_IN    1024
#define B_SZ    8
#define T_STEPS 500
#define NSLICE  16
#define NBLK    (B_SZ * NSLICE)     // 128 blocks, 256 threads, 1 post/thread
#define FF_WORDS (B_SZ * T_STEPS * 16)

// ws layout:
//   [0)      int seq[8][64]        2 KB   (per-batch 64B seq line, 256B stride)
//   [2048)   u64 tmask[64]         512 B  (per-64-group exc-type bit masks)
//   [2560)   u64 mb[2][8][64]      8 KB   (dbuf spike masks, 64 words/batch)
//   [10752)  u64 ffmask[B*T*16]    512 KB (input-spike bitmasks)
#define WS_SEQ_OFF   0
#define WS_TM_OFF    2048
#define WS_MB_OFF    2560
#define WS_FFM_OFF   10752

__global__ __launch_bounds__(64) void snn_init(const int* __restrict__ ci,
                                               int* __restrict__ seq,
                                               unsigned long long* __restrict__ tmask,
                                               unsigned long long* __restrict__ mb) {
    const int k = blockIdx.x, l = threadIdx.x;   // 64 blocks x 64 threads
    unsigned long long m = __ballot(ci[(k << 6) + l] == 0);
    if (l == 0) tmask[k] = m;
    const int idx = (k << 6) + l;
    if (idx < 512)  seq[idx] = 0;
    if (idx < 1024) mb[idx] = 0ULL;
}

// input spikes (B,T,NI) -> bitmask words, 64 elems per word, ascending order
__global__ __launch_bounds__(256) void snn_ffmask(const float* __restrict__ inspk,
                                                  unsigned long long* __restrict__ ffmask) {
    int gid = blockIdx.x * 256 + threadIdx.x;
    int wid = gid >> 6, lane = gid & 63;
    int nw  = (gridDim.x * 256) >> 6;
    for (int w = wid; w < FF_WORDS; w += nw) {
        float v = inspk[(size_t)w * 64 + lane];
        unsigned long long m = __ballot(v > 0.5f);
        if (lane == 0) ffmask[w] = m;
    }
}

// Extract set-bit indices of a distributed 64x64-bit mask (lane l holds word l,
// bit b -> index l*64+b) into lds as typed entries (idx<<2)|ty, globally
// ascending; ty from tm_exc (bit set -> ty0/exc, clear -> ty1/inh). Pads to a
// multiple of 64 with sentinel entries (idx 0, ty 2). Returns real count.
__device__ __forceinline__ int extract_pad(unsigned long long m,
                                           unsigned long long tm_exc,
                                           int* lds, int lane) {
    int pc  = __popcll(m);
    int sum = pc;
#pragma unroll
    for (int d = 1; d < 64; d <<= 1) {
        int o = __shfl_up(sum, d, 64);
        if (lane >= d) sum += o;
    }
    int off   = sum - pc;           // exclusive prefix
    int total = __shfl(sum, 63, 64);
    int base  = lane << 6;
    while (m) {
        int bit = __builtin_ctzll(m);
        int ty  = ((tm_exc >> bit) & 1ULL) ? 0 : 1;
        lds[off++] = ((base + bit) << 2) | ty;
        m &= m - 1ULL;
    }
    int padcnt = (-total) & 63;
    if (lane < padcnt) lds[total + lane] = 2;   // sentinel: idx 0, ty 2
    return total;
}

// Combined typed gather: 64-deep pipelined loop over a padded entry list;
// exc/inh accumulate into SEPARATE accumulators (each internally ascending ->
// bit-exact vs reference's separate matmuls). Sentinels (ty2) contribute 0.
__device__ __forceinline__ void gather2(const int* __restrict__ lst, int npad,
                                        const float* __restrict__ base,
                                        float se, float si,
                                        float* oe, float* oi) {
#pragma clang fp contract(off)
    float ae = 0.0f, ai = 0.0f;
    for (int k = 0; k < npad; k += 64) {
        int   e[64];
        float w[64];
#pragma unroll
        for (int u = 0; u < 64; ++u) e[u] = lst[k + u];
#pragma unroll
        for (int u = 0; u < 64; ++u) w[u] = base[(size_t)(e[u] >> 2) << 12];
#pragma unroll
        for (int u = 0; u < 64; ++u) {
            const int ty = e[u] & 3;
            const float sc = (ty == 0) ? se : ((ty == 1) ? si : 0.0f);
            const float p  = w[u] * sc;           // per-element product rounding = W_eff
            ae = (ty == 0) ? ae + p : ae;
            ai = (ty == 1) ? ai + p : ai;
        }
    }
    *oe = ae; *oi = ai;
}

__global__ __launch_bounds__(256, 1) void snn_run(
    const float* __restrict__ W,       // (N,N) row j = presyn
    const float* __restrict__ Wff,     // (NI,N)
    const float* __restrict__ sf,      // (2,2)
    const float* __restrict__ sfff,    // (1,2)
    const int*   __restrict__ ci,      // (N)
    float*       __restrict__ out,     // (B,T,N)
    const unsigned long long* __restrict__ ffmask,
    const unsigned long long* __restrict__ tmask_g,
    int*         __restrict__ seq,
    unsigned long long* __restrict__ mb)
{
#pragma clang fp contract(off)
    const int tid   = threadIdx.x;
    const int lane  = tid & 63;
    const int wv    = tid >> 6;
    const int bid   = blockIdx.x;
    // slice from bits {0,1,2,6} (slice%8 pins W col-slice groups per XCD),
    // batch from bits {3,4,5}
    const int slice = (((bid >> 6) & 1) << 3) | (bid & 7);
    const int b     = (bid >> 3) & 7;
    const int i     = (slice << 8) + (wv << 6) + lane;    // my post neuron
    const int c     = ci[i];

    const float s_exc = sf[c];
    const float s_inh = sf[2 + c];
    const float s_ff  = sfff[c];

    const unsigned long long my_tm = tmask_g[lane];   // wave0's extract role

    __shared__ int lds_c[N_NEU + 64];
    __shared__ int lds_f[N_IN + 64];
    __shared__ int s_ne, s_nf;

    int* seqb = seq + b * 64;                             // one 64B line
    unsigned long long* mb_b[2] = { mb + (size_t)b * 64, mb + 512 + (size_t)b * 64 };

    // state lives in registers for all 500 steps (1 post/thread)
    float v = -70.0f, rf = 0.0f;
    float h0 = 0.0f, h1 = 0.0f, h2 = 0.0f, h3 = 0.0f;
    float g0 = 0.0f, g1 = 0.0f, g2 = 0.0f, g3 = 0.0f;

    const float aR0 = expf(-0.1f / 0.5f);
    const float aR1 = expf(-0.1f / 2.0f);
    const float aD0 = expf(-0.1f / 2.0f);
    const float aD1 = expf(-0.1f / 100.0f);
    const float aD2 = expf(-0.1f / 5.0f);
    const float kmem   = c ? (0.1f / 10.0f) : (0.1f / 20.0f);
    const float rsteps = c ? 10.0f : 20.0f;

    for (int t = 0; t < T_STEPS; ++t) {
        if (wv == 0) {
            if (t > 0) {
                // single-line poll (64B), wave0 only: 128 poller waves device-
                // wide, payload fetched ONCE after the poll (R6/R8 lesson:
                // poll bytes are a first-class cost at agent scope).
                for (;;) {
                    int sv = (lane < NSLICE)
                        ? __hip_atomic_load(&seqb[lane], __ATOMIC_RELAXED,
                                            __HIP_MEMORY_SCOPE_AGENT)
                        : t;
                    if (__ballot(sv >= t) == ~0ULL) break;
                    __builtin_amdgcn_s_sleep(1);
                }
                asm volatile("" ::: "memory");   // keep mask loads below the poll
            }
            unsigned long long mw = 0ULL;
            if (t > 0)
                mw = __hip_atomic_load(&mb_b[t & 1][lane], __ATOMIC_RELAXED,
                                       __HIP_MEMORY_SCOPE_AGENT);
            const int n = extract_pad(mw, my_tm, lds_c, lane);
            if (lane == 0) s_ne = n;
        } else if (wv == 1) {
            // ff extraction is poll-independent: runs concurrently with wave0's
            // poll, so it's off the critical chain entirely.
            const unsigned long long mf =
                (lane < 16) ? ffmask[((size_t)b * T_STEPS + t) * 16 + lane] : 0ULL;
            const int nf = extract_pad(mf, ~0ULL, lds_f, lane);   // all ty0
            if (lane == 0) s_nf = nf;
        }
        __syncthreads();   // A: lists + counts visible to all 4 waves

        float exc, inh, ffd, dummy;
        gather2(lds_c, (s_ne + 63) & ~63, W + i, s_exc, s_inh, &exc, &inh);
        gather2(lds_f, (s_nf + 63) & ~63, Wff + i, s_ff, 0.0f, &ffd, &dummy);

        // ---- neuron update (identical fp op sequence to R1–R8: bit-exact) ----
        const float d0 = exc;
        const float d1 = 0.5f * exc;
        const float d2 = inh;
        const float d3 = ffd;

        h0 = fmaf(h0, aR0, d0);
        h1 = fmaf(h1, aR1, d1);
        h2 = fmaf(h2, aR0, d2);
        h3 = fmaf(h3, aR0, d3);
        g0 = fmaf(g0, aD0, (1.0f - aD0) * h0);
        g1 = fmaf(g1, aD1, (1.0f - aD1) * h1);
        g2 = fmaf(g2, aD2, (1.0f - aD2) * h2);
        g3 = fmaf(g3, aD0, (1.0f - aD0) * h3);

        const float p0 = g0 * (0.0f - v);
        const float p1 = g1 * (0.0f - v);
        const float p2 = g2 * (-80.0f - v);
        const float p3 = g3 * (0.0f - v);
        const float Isyn = ((p0 + p1) + p2) + p3;

        float vn = fmaf(kmem, (-70.0f - v) + Isyn / 10.0f, v);
        const bool refr = rf > 0.0f;
        if (refr) vn = -65.0f;
        const float sn = (!refr && (vn > -50.0f)) ? 1.0f : 0.0f;
        const bool spk = sn > 0.5f;
        v  = spk ? -65.0f : vn;
        rf = spk ? rsteps : fmaxf(rf - 1.0f, 0.0f);

        // publish this wave's 64-post spike word for step t+1; seq-critical
        // chain excludes the out store (issued after the seq publish).
        const unsigned long long sm = __ballot(spk);
        if (lane == 0)
            __hip_atomic_store(&mb_b[(t + 1) & 1][(slice << 2) | wv], sm,
                               __ATOMIC_RELAXED, __HIP_MEMORY_SCOPE_AGENT);
        __builtin_amdgcn_s_waitcnt(0);   // drain mask word (only) to IF
        __syncthreads();                 // B: all 4 words of this block drained
        if (wv == 0 && lane == 0)
            __hip_atomic_store(&seqb[slice], t + 1,
                               __ATOMIC_RELAXED, __HIP_MEMORY_SCOPE_AGENT);
        out[((size_t)b * T_STEPS + t) * N_NEU + i] = sn;   // fire-and-forget
        // wave0 proceeds to poll t+1; others park at A. lds_c rewrite is safe:
        // wave0 can't pass its own poll until this block's seq (post-B) landed,
        // and B follows every lds read of step t.
    }
}

extern "C" void kernel_launch(void* const* d_in, const int* in_sizes, int n_in,
                              void* d_out, int out_size, void* d_ws, size_t ws_size,
                              hipStream_t stream) {
    const float* inspk = (const float*)d_in[0];
    const float* W     = (const float*)d_in[1];
    const float* Wff   = (const float*)d_in[2];
    const float* sf    = (const float*)d_in[3];
    const float* sfff  = (const float*)d_in[4];
    const int*   ci    = (const int*)d_in[5];

    float* out = (float*)d_out;
    int*                seq    = (int*)((char*)d_ws + WS_SEQ_OFF);
    unsigned long long* tmask  = (unsigned long long*)((char*)d_ws + WS_TM_OFF);
    unsigned long long* mb     = (unsigned long long*)((char*)d_ws + WS_MB_OFF);
    unsigned long long* ffmask = (unsigned long long*)((char*)d_ws + WS_FFM_OFF);

    snn_init<<<64, 64, 0, stream>>>(ci, seq, tmask, mb);
    snn_ffmask<<<1000, 256, 0, stream>>>(inspk, ffmask);
    snn_run<<<NBLK, 256, 0, stream>>>(W, Wff, sf, sfff, ci, out,
                                      ffmask, tmask, seq, mb);
}

// Round 10
// 1708.652 us; speedup vs baseline: 2.0253x; 1.3591x over previous
//
#include <hip/hip_runtime.h>
#include <cstdint>
#include <cstddef>

// Problem constants
#define N_NEU   4096
#define N_IN    1024
#define B_SZ    8
#define T_STEPS 500
#define NSLICE  16
#define NBLK    (B_SZ * NSLICE)     // 128 blocks, 256 threads, 1 post/thread
#define FF_WORDS (B_SZ * T_STEPS * 16)

// ws layout:
//   [0)       int seq[8][64]        2 KB   (per-batch 64B seq line, 256B stride)
//   [2048)    u64 tmask[64]         512 B  (per-64-group exc-type bit masks)
//   [2560)    u64 mb[2][8][64]      8 KB   (dbuf spike masks, 64 words/batch)
//   [10752)   u64 ffmask[B*T*16]    512 KB (input-spike bitmasks)
//   [522752)  float ffdrive[T][B][N] 65.5 MB (precomputed FF drive)
#define WS_SEQ_OFF   0
#define WS_TM_OFF    2048
#define WS_MB_OFF    2560
#define WS_FFM_OFF   10752
#define WS_FFD_OFF   522752
#define WS_NEED_FFD  (522752 + (size_t)T_STEPS * B_SZ * N_NEU * 4)

__global__ __launch_bounds__(64) void snn_init(const int* __restrict__ ci,
                                               int* __restrict__ seq,
                                               unsigned long long* __restrict__ tmask,
                                               unsigned long long* __restrict__ mb) {
    const int k = blockIdx.x, l = threadIdx.x;   // 64 blocks x 64 threads
    unsigned long long m = __ballot(ci[(k << 6) + l] == 0);
    if (l == 0) tmask[k] = m;
    const int idx = (k << 6) + l;
    if (idx < 512)  seq[idx] = 0;
    if (idx < 1024) mb[idx] = 0ULL;
}

// input spikes (B,T,NI) -> bitmask words, 64 elems per word, ascending order
__global__ __launch_bounds__(256) void snn_ffmask(const float* __restrict__ inspk,
                                                  unsigned long long* __restrict__ ffmask) {
    int gid = blockIdx.x * 256 + threadIdx.x;
    int wid = gid >> 6, lane = gid & 63;
    int nw  = (gridDim.x * 256) >> 6;
    for (int w = wid; w < FF_WORDS; w += nw) {
        float v = inspk[(size_t)w * 64 + lane];
        unsigned long long m = __ballot(v > 0.5f);
        if (lane == 0) ffmask[w] = m;
    }
}

// Extract set-bit indices of a distributed 64x64-bit mask (lane l holds word l,
// bit b -> index l*64+b) into lds as typed entries (idx<<2)|ty, globally
// ascending; ty from tm_exc (bit set -> ty0/exc, clear -> ty1/inh). Pads to a
// multiple of 64 with sentinel entries (idx 0, ty 2). Returns real count.
__device__ __forceinline__ int extract_pad(unsigned long long m,
                                           unsigned long long tm_exc,
                                           int* lds, int lane) {
    int pc  = __popcll(m);
    int sum = pc;
#pragma unroll
    for (int d = 1; d < 64; d <<= 1) {
        int o = __shfl_up(sum, d, 64);
        if (lane >= d) sum += o;
    }
    int off   = sum - pc;           // exclusive prefix
    int total = __shfl(sum, 63, 64);
    int base  = lane << 6;
    while (m) {
        int bit = __builtin_ctzll(m);
        int ty  = ((tm_exc >> bit) & 1ULL) ? 0 : 1;
        lds[off++] = ((base + bit) << 2) | ty;
        m &= m - 1ULL;
    }
    int padcnt = (-total) & 63;
    if (lane < padcnt) lds[total + lane] = 2;   // sentinel: idx 0, ty 2
    return total;
}

// Combined typed gather: 64-deep pipelined loop over a padded entry list;
// exc/inh accumulate into SEPARATE accumulators (each internally ascending ->
// bit-exact vs reference's separate matmuls). Sentinels (ty2) contribute 0.
__device__ __forceinline__ void gather2(const int* __restrict__ lst, int npad,
                                        const float* __restrict__ base,
                                        float se, float si,
                                        float* oe, float* oi) {
#pragma clang fp contract(off)
    float ae = 0.0f, ai = 0.0f;
    for (int k = 0; k < npad; k += 64) {
        int   e[64];
        float w[64];
#pragma unroll
        for (int u = 0; u < 64; ++u) e[u] = lst[k + u];
#pragma unroll
        for (int u = 0; u < 64; ++u) w[u] = base[(size_t)(e[u] >> 2) << 12];
#pragma unroll
        for (int u = 0; u < 64; ++u) {
            const int ty = e[u] & 3;
            const float sc = (ty == 0) ? se : ((ty == 1) ? si : 0.0f);
            const float p  = w[u] * sc;           // per-element product rounding = W_eff
            ae = (ty == 0) ? ae + p : ae;
            ai = (ty == 1) ? ai + p : ai;
        }
    }
    *oe = ae; *oi = ai;
}

// Precompute FF drive for all (t,b) from ffmask (128 B/pair, not 4 KB inspk —
// R7's ffpre re-read inspk 64x redundantly; this was most of its 450 us gap).
__global__ __launch_bounds__(64) void snn_ffpre(const unsigned long long* __restrict__ ffmask,
                                                const float* __restrict__ Wff,
                                                const float* __restrict__ sfff,
                                                const int*   __restrict__ ci,
                                                float*       __restrict__ ffdrive) {
#pragma clang fp contract(off)
    const int lane  = threadIdx.x;
    const int chunk = blockIdx.x & 63;
    const int tile  = blockIdx.x >> 6;     // 160 tiles of 25 (t,b) pairs
    const int i     = (chunk << 6) + lane;
    const float s_ff = sfff[ci[i]];
    __shared__ int lds_f[N_IN + 64];
    for (int p = tile * 25; p < tile * 25 + 25; ++p) {
        const int t = p >> 3, b = p & 7;
        const unsigned long long mf =
            (lane < 16) ? ffmask[((size_t)b * T_STEPS + t) * 16 + lane] : 0ULL;
        const int n = extract_pad(mf, ~0ULL, lds_f, lane);   // all ty0
        float fd, dummy;
        gather2(lds_f, (n + 63) & ~63, Wff + i, s_ff, 0.0f, &fd, &dummy);
        ffdrive[((size_t)t * B_SZ + b) * N_NEU + i] = fd;
    }
}

__global__ __launch_bounds__(256) void snn_run(
    const float* __restrict__ W,       // (N,N) row j = presyn
    const float* __restrict__ Wff,     // (NI,N)
    const float* __restrict__ sf,      // (2,2)
    const float* __restrict__ sfff,    // (1,2)
    const int*   __restrict__ ci,      // (N)
    float*       __restrict__ out,     // (B,T,N)
    const unsigned long long* __restrict__ ffmask,
    const unsigned long long* __restrict__ tmask_g,
    const float* __restrict__ ffdrive,
    int use_ffpre,
    int*         __restrict__ seq,
    unsigned long long* __restrict__ mb)
{
#pragma clang fp contract(off)
    const int tid   = threadIdx.x;
    const int lane  = tid & 63;
    const int wv    = tid >> 6;
    const int bid   = blockIdx.x;
    // slice from bits {0,1,2,6} (slice%8 pins W col-slice groups per XCD),
    // batch from bits {3,4,5}
    const int slice = (((bid >> 6) & 1) << 3) | (bid & 7);
    const int b     = (bid >> 3) & 7;
    const int i     = (slice << 8) + (wv << 6) + lane;    // my post neuron
    const int c     = ci[i];

    const float s_exc = sf[c];
    const float s_inh = sf[2 + c];
    const float s_ff  = sfff[c];

    const unsigned long long my_tm = tmask_g[lane];   // wave0's extract role

    __shared__ int lds_c[N_NEU + 64];
    __shared__ int lds_f[N_IN + 64];
    __shared__ int s_ne, s_nf;

    int* seqb = seq + b * 64;                             // one 64B line
    unsigned long long* mb_b[2] = { mb + (size_t)b * 64, mb + 512 + (size_t)b * 64 };

    // state lives in registers for all 500 steps (1 post/thread)
    float v = -70.0f, rf = 0.0f;
    float h0 = 0.0f, h1 = 0.0f, h2 = 0.0f, h3 = 0.0f;
    float g0 = 0.0f, g1 = 0.0f, g2 = 0.0f, g3 = 0.0f;

    const float aR0 = expf(-0.1f / 0.5f);
    const float aR1 = expf(-0.1f / 2.0f);
    const float aD0 = expf(-0.1f / 2.0f);
    const float aD1 = expf(-0.1f / 100.0f);
    const float aD2 = expf(-0.1f / 5.0f);
    const float kmem   = c ? (0.1f / 10.0f) : (0.1f / 20.0f);
    const float rsteps = c ? 10.0f : 20.0f;

    for (int t = 0; t < T_STEPS; ++t) {
        if (wv == 0) {
            if (t > 0) {
                // single-line poll (64B), wave0 only; payload fetched ONCE
                // after the poll passes (R6/R8 lesson: poll bytes x pollers
                // is a first-class cost at agent scope).
                for (;;) {
                    int sv = (lane < NSLICE)
                        ? __hip_atomic_load(&seqb[lane], __ATOMIC_RELAXED,
                                            __HIP_MEMORY_SCOPE_AGENT)
                        : t;
                    if (__ballot(sv >= t) == ~0ULL) break;
                    __builtin_amdgcn_s_sleep(1);
                }
                asm volatile("" ::: "memory");   // keep mask loads below the poll
            }
            unsigned long long mw = 0ULL;
            if (t > 0)
                mw = __hip_atomic_load(&mb_b[t & 1][lane], __ATOMIC_RELAXED,
                                       __HIP_MEMORY_SCOPE_AGENT);
            const int n = extract_pad(mw, my_tm, lds_c, lane);
            if (lane == 0) s_ne = n;
            if (!use_ffpre) {
                const unsigned long long mf =
                    (lane < 16) ? ffmask[((size_t)b * T_STEPS + t) * 16 + lane] : 0ULL;
                const int nf = extract_pad(mf, ~0ULL, lds_f, lane);
                if (lane == 0) s_nf = nf;
            }
        }
        __syncthreads();   // A: lists + counts published to all 4 waves

        float ffd = 0.0f;
        if (use_ffpre)
            ffd = ffdrive[((size_t)t * B_SZ + b) * N_NEU + i];  // issued early

        float exc, inh;
        gather2(lds_c, (s_ne + 63) & ~63, W + i, s_exc, s_inh, &exc, &inh);
        if (!use_ffpre) {
            float fd, dummy;
            gather2(lds_f, (s_nf + 63) & ~63, Wff + i, s_ff, 0.0f, &fd, &dummy);
            ffd = fd;
        }

        // ---- neuron update (identical fp op sequence to R1–R9: bit-exact) ----
        const float d0 = exc;
        const float d1 = 0.5f * exc;
        const float d2 = inh;
        const float d3 = ffd;

        h0 = fmaf(h0, aR0, d0);
        h1 = fmaf(h1, aR1, d1);
        h2 = fmaf(h2, aR0, d2);
        h3 = fmaf(h3, aR0, d3);
        g0 = fmaf(g0, aD0, (1.0f - aD0) * h0);
        g1 = fmaf(g1, aD1, (1.0f - aD1) * h1);
        g2 = fmaf(g2, aD2, (1.0f - aD2) * h2);
        g3 = fmaf(g3, aD0, (1.0f - aD0) * h3);

        const float p0 = g0 * (0.0f - v);
        const float p1 = g1 * (0.0f - v);
        const float p2 = g2 * (-80.0f - v);
        const float p3 = g3 * (0.0f - v);
        const float Isyn = ((p0 + p1) + p2) + p3;

        float vn = fmaf(kmem, (-70.0f - v) + Isyn / 10.0f, v);
        const bool refr = rf > 0.0f;
        if (refr) vn = -65.0f;
        const float sn = (!refr && (vn > -50.0f)) ? 1.0f : 0.0f;
        const bool spk = sn > 0.5f;
        v  = spk ? -65.0f : vn;
        rf = spk ? rsteps : fmaxf(rf - 1.0f, 0.0f);

        // publish this wave's 64-post spike word for step t+1. The out store
        // is issued AFTER the seq publish so the waitcnt drains only 8 bytes.
        const unsigned long long sm = __ballot(spk);
        if (lane == 0)
            __hip_atomic_store(&mb_b[(t + 1) & 1][(slice << 2) | wv], sm,
                               __ATOMIC_RELAXED, __HIP_MEMORY_SCOPE_AGENT);
        __builtin_amdgcn_s_waitcnt(0);   // drain my mask word to IF
        __syncthreads();                 // B: all 4 words of this block drained
        if (wv == 0 && lane == 0)
            __hip_atomic_store(&seqb[slice], t + 1,
                               __ATOMIC_RELAXED, __HIP_MEMORY_SCOPE_AGENT);
        out[((size_t)b * T_STEPS + t) * N_NEU + i] = sn;   // fire-and-forget
        // wave0 proceeds to poll t+1; other waves park at A — lds rewrite is
        // safe (B followed every lds read of step t, and wave0 can't pass its
        // own poll until this block's seq landed).
    }
}

extern "C" void kernel_launch(void* const* d_in, const int* in_sizes, int n_in,
                              void* d_out, int out_size, void* d_ws, size_t ws_size,
                              hipStream_t stream) {
    const float* inspk = (const float*)d_in[0];
    const float* W     = (const float*)d_in[1];
    const float* Wff   = (const float*)d_in[2];
    const float* sf    = (const float*)d_in[3];
    const float* sfff  = (const float*)d_in[4];
    const int*   ci    = (const int*)d_in[5];

    float* out = (float*)d_out;
    int*                seq     = (int*)((char*)d_ws + WS_SEQ_OFF);
    unsigned long long* tmask   = (unsigned long long*)((char*)d_ws + WS_TM_OFF);
    unsigned long long* mb      = (unsigned long long*)((char*)d_ws + WS_MB_OFF);
    unsigned long long* ffmask  = (unsigned long long*)((char*)d_ws + WS_FFM_OFF);
    float*              ffdrive = (float*)((char*)d_ws + WS_FFD_OFF);
    const int use_ffpre = (ws_size >= WS_NEED_FFD) ? 1 : 0;

    snn_init<<<64, 64, 0, stream>>>(ci, seq, tmask, mb);
    snn_ffmask<<<1000, 256, 0, stream>>>(inspk, ffmask);
    if (use_ffpre)
        snn_ffpre<<<160 * 64, 64, 0, stream>>>(ffmask, Wff, sfff, ci, ffdrive);
    snn_run<<<NBLK, 256, 0, stream>>>(W, Wff, sf, sfff, ci, out,
                                      ffmask, tmask, ffdrive, use_ffpre, seq, mb);
}